// Round 9
// baseline (257.693 us; speedup 1.0000x reference)
//
#include <hip/hip_runtime.h>
#include <hip/hip_bf16.h>

// ---------------- types / helpers ----------------
typedef __attribute__((ext_vector_type(8))) short bf16x8;
typedef __attribute__((ext_vector_type(4))) float f32x4;

#define T_TOK 2048
#define HD 1024
#define ID 512
#define NE 16
#define TOPK 4
#define BK 64            // K-panel depth (bf16)
#define WELEM (HD*ID*NE) // elems per weight tensor = 8388608

// pack two fp32 -> two bf16 (truncate): one v_perm_b32
__device__ __forceinline__ unsigned pk2(float a, float b) {
    return __builtin_amdgcn_perm(__float_as_uint(b), __float_as_uint(a),
                                 0x07060302u);
}
__device__ __forceinline__ bf16x8 cvt8(const float* __restrict__ p) {
    float4 a = *(const float4*)p;
    float4 b = *(const float4*)(p + 4);
    union { bf16x8 v; unsigned u[4]; } r;
    r.u[0] = pk2(a.x, a.y); r.u[1] = pk2(a.z, a.w);
    r.u[2] = pk2(b.x, b.y); r.u[3] = pk2(b.z, b.w);
    return r.v;
}
__device__ __forceinline__ short f2bf(float f) {  // RTNE
    unsigned u = __float_as_uint(f);
    return (short)((u + 0x7fffu + ((u >> 16) & 1u)) >> 16);
}
__device__ __forceinline__ float bf2f(short s) {
    return __uint_as_float(((unsigned)(unsigned short)s) << 16);
}
// async 16B-per-lane global->LDS DMA; lds dest = wave-uniform base + lane*16
__device__ __forceinline__ void load_lds16(const short* g, short* l) {
    __builtin_amdgcn_global_load_lds(
        (const __attribute__((address_space(1))) unsigned*)g,
        (__attribute__((address_space(3))) unsigned*)l, 16, 0, 0);
}

#define MFMA_BF16 __builtin_amdgcn_mfma_f32_16x16x32_bf16

// ---------------- kernel 0: fp32 -> bf16 convert (3 tensors) --------------
__global__ __launch_bounds__(256) void conv_k(
        const float* __restrict__ s0, short* __restrict__ d0,
        const float* __restrict__ s1, short* __restrict__ d1,
        const float* __restrict__ s2, short* __restrict__ d2) {
    const float* src = (blockIdx.y == 0) ? s0 : (blockIdx.y == 1) ? s1 : s2;
    short* dst       = (blockIdx.y == 0) ? d0 : (blockIdx.y == 1) ? d1 : d2;
    size_t i = ((size_t)blockIdx.x * 256 + threadIdx.x) * 8;
    union { bf16x8 v; uint4 q; } r;
    r.v = cvt8(src + i);
    *(uint4*)(dst + i) = r.q;
}

// ---------------- kernel 1: router (+ x -> bf16) ----------------
__global__ __launch_bounds__(256) void router_k(
        const float* __restrict__ x, const float* __restrict__ gw,
        const float* __restrict__ eb,
        int* __restrict__ tk_idx, float* __restrict__ tk_w,
        short* __restrict__ xb) {
    int wid  = (blockIdx.x * 256 + threadIdx.x) >> 6;   // token id
    int lane = threadIdx.x & 63;

    const float* xr = x + (size_t)wid * HD + lane * 16;
    float xv[16];
#pragma unroll
    for (int c = 0; c < 4; c++) {
        float4 v = *(const float4*)(xr + c * 4);
        xv[4 * c] = v.x; xv[4 * c + 1] = v.y; xv[4 * c + 2] = v.z; xv[4 * c + 3] = v.w;
    }
    {   // bf16 copy of x, coalesced
        union { uint4 q; unsigned u[4]; } w0, w1;
        w0.u[0] = pk2(xv[0], xv[1]);  w0.u[1] = pk2(xv[2], xv[3]);
        w0.u[2] = pk2(xv[4], xv[5]);  w0.u[3] = pk2(xv[6], xv[7]);
        w1.u[0] = pk2(xv[8], xv[9]);  w1.u[1] = pk2(xv[10], xv[11]);
        w1.u[2] = pk2(xv[12], xv[13]); w1.u[3] = pk2(xv[14], xv[15]);
        short* d = xb + ((size_t)wid << 10) + lane * 16;
        *(uint4*)d = w0.q;
        *(uint4*)(d + 8) = w1.q;
    }

    float logits[NE];
#pragma unroll
    for (int e = 0; e < NE; e++) {
        const float* gr = gw + e * HD + lane * 16;
        float p = 0.f;
#pragma unroll
        for (int c = 0; c < 4; c++) {
            float4 v = *(const float4*)(gr + c * 4);
            p += xv[4 * c] * v.x + xv[4 * c + 1] * v.y +
                 xv[4 * c + 2] * v.z + xv[4 * c + 3] * v.w;
        }
#pragma unroll
        for (int s = 32; s > 0; s >>= 1) p += __shfl_xor(p, s, 64);
        logits[e] = p;
    }

    float scores[NE], sc[NE];
#pragma unroll
    for (int e = 0; e < NE; e++) {
        scores[e] = 1.f / (1.f + __expf(-logits[e]));
        sc[e] = scores[e] + eb[e];
    }

    float gs[4];
#pragma unroll
    for (int g = 0; g < 4; g++) {
        float a = sc[4 * g], b = sc[4 * g + 1], c = sc[4 * g + 2], d = sc[4 * g + 3];
        float h1 = fmaxf(a, b), l1 = fminf(a, b);
        float h2 = fmaxf(c, d), l2 = fminf(c, d);
        gs[g] = fmaxf(h1, h2) + fmaxf(fminf(h1, h2), fmaxf(l1, l2));
    }
    int g0 = 0; float b0 = gs[0];
#pragma unroll
    for (int g = 1; g < 4; g++) if (gs[g] > b0) { b0 = gs[g]; g0 = g; }
    int g1 = -1; float b1 = -1e30f;
#pragma unroll
    for (int g = 0; g < 4; g++) if (g != g0 && gs[g] > b1) { b1 = gs[g]; g1 = g; }

    int taken = 0;
    int bid[TOPK]; float bsc[TOPK]; float wsum = 0.f;
#pragma unroll
    for (int k = 0; k < TOPK; k++) {
        float bv = -1e30f; int bi = 0; float bs = 0.f;
#pragma unroll
        for (int e = 0; e < NE; e++) {
            int grp = e >> 2;
            bool ok = ((grp == g0) || (grp == g1)) && !((taken >> e) & 1);
            if (ok && sc[e] > bv) { bv = sc[e]; bi = e; bs = scores[e]; }
        }
        taken |= (1 << bi);
        bid[k] = bi; bsc[k] = bs; wsum += bs;
    }
    if (lane == 0) {
        float inv = 1.0f / (wsum + 1e-20f);
#pragma unroll
        for (int k = 0; k < TOPK; k++) {
            tk_idx[wid * TOPK + k] = bid[k];
            tk_w[wid * TOPK + k]   = bsc[k] * inv;
        }
    }
}

// ---------------- kernel 2: per-expert token lists ----------------
__global__ __launch_bounds__(256) void assign_k(
        const int* __restrict__ tk_idx,
        int* __restrict__ counts, int* __restrict__ tok_list,
        int* __restrict__ pair_slot) {
    int p = blockIdx.x * 256 + threadIdx.x;   // pair id < T_TOK*TOPK
    int e = tk_idx[p];
    int slot = atomicAdd(&counts[e], 1);
    tok_list[e * T_TOK + slot] = p >> 2;
    pair_slot[p] = slot;
}

__global__ void offs_k(const int* __restrict__ counts, int* __restrict__ offs) {
    if (threadIdx.x == 0) {
        int a = 0;
#pragma unroll
        for (int e = 0; e < NE; e++) { offs[e] = a; a += counts[e]; }
    }
}

// ---------------- kernel 3: GEMM1 (x @ [gate|up]^T, silu*up -> act) -------
// grid (n_slices=8, m_tiles=16, experts=16). block tile M=128 x N=64
// (gate AND up), BK=64, 4 waves (2x2), wave 64x32.
// Double-buffered global_load_lds: DMA(k+1) issued right after barrier(k),
// in flight during compute(k); barrier(k+1)'s vmcnt drain pays only the
// remainder. XOR chunk swizzle on SOURCE address; LDS layout linear.
__global__ __launch_bounds__(256) void gemm1_k(
        const short* __restrict__ xb,
        const short* __restrict__ gpb,
        const short* __restrict__ upb,
        const int* __restrict__ counts,
        const int* __restrict__ offs,
        const int* __restrict__ tok_list,
        short* __restrict__ act) {
    __shared__ short xs[2 * 128 * BK];
    __shared__ short gs[2 * 64 * BK];
    __shared__ short us[2 * 64 * BK];
    __shared__ int   tok_s[128];

    int e = blockIdx.z;
    int cnt = counts[e];
    int base = blockIdx.y * 128;
    if (base >= cnt) return;
    int arow0 = offs[e] + base;

    int tid = threadIdx.x;
    if (tid < 128) {
        int s = base + tid;
        tok_s[tid] = (s < cnt) ? tok_list[e * T_TOK + s] : tok_list[e * T_TOK];
    }
    __syncthreads();

    int wv = tid >> 6, lane = tid & 63;
    int qd = lane >> 4, l16 = lane & 15;
    int wm = (wv >> 1) * 64, wn = (wv & 1) * 32;
    int nb0 = blockIdx.x * 64;
    const short* gp = gpb + (size_t)e * ID * HD + (size_t)nb0 * HD;
    const short* up = upb + (size_t)e * ID * HD + (size_t)nb0 * HD;

    // per-lane swizzled global sources + wave-uniform LDS dest bases (buf 0)
    const short* xsg[4]; short* xld[4];
#pragma unroll
    for (int i = 0; i < 4; i++) {
        int idx = i * 256 + tid, r = idx >> 3, c = idx & 7;
        xsg[i] = xb + ((size_t)tok_s[r] << 10) + (((c ^ r) & 7) << 3);
        xld[i] = &xs[(i * 256 + wv * 64) * 8];
    }
    const short* gsg[2]; const short* usg[2]; short* gld[2]; short* uld[2];
#pragma unroll
    for (int i = 0; i < 2; i++) {
        int idx = i * 256 + tid, r = idx >> 3, c = idx & 7;
        size_t so = (size_t)r * HD + (((c ^ r) & 7) << 3);
        gsg[i] = gp + so;
        usg[i] = up + so;
        gld[i] = &gs[(i * 256 + wv * 64) * 8];
        uld[i] = &us[(i * 256 + wv * 64) * 8];
    }

    f32x4 accg[4][2] = {};
    f32x4 accu[4][2] = {};

    // pre-issue panel 0 into buffer 0
#pragma unroll
    for (int i = 0; i < 4; i++) load_lds16(xsg[i], xld[i]);
#pragma unroll
    for (int i = 0; i < 2; i++) {
        load_lds16(gsg[i], gld[i]);
        load_lds16(usg[i], uld[i]);
    }

    for (int kpi = 0; kpi < HD / BK; kpi++) {
        __syncthreads();   // DMA(kpi) landed; compute(kpi-1) readers done
        if (kpi + 1 < HD / BK) {   // DMA(kpi+1) -> other buffer
            int kn = (kpi + 1) * BK;
            int xo = ((kpi + 1) & 1) * 128 * BK;
            int bo = ((kpi + 1) & 1) * 64 * BK;
#pragma unroll
            for (int i = 0; i < 4; i++) load_lds16(xsg[i] + kn, xld[i] + xo);
#pragma unroll
            for (int i = 0; i < 2; i++) {
                load_lds16(gsg[i] + kn, gld[i] + bo);
                load_lds16(usg[i] + kn, uld[i] + bo);
            }
        }
        const short* xsb = &xs[(kpi & 1) * 128 * BK];
        const short* gsb = &gs[(kpi & 1) * 64 * BK];
        const short* usb = &us[(kpi & 1) * 64 * BK];
#pragma unroll
        for (int ks = 0; ks < 2; ks++) {
            int cb = ks * 4 + qd;
            bf16x8 af[4], bg[2], bu[2];
#pragma unroll
            for (int i = 0; i < 4; i++) {
                int r = wm + i * 16 + l16;
                af[i] = *(const bf16x8*)&xsb[(r << 6) + (((cb ^ r) & 7) << 3)];
            }
#pragma unroll
            for (int j = 0; j < 2; j++) {
                int r = wn + j * 16 + l16;
                int lo = (r << 6) + (((cb ^ r) & 7) << 3);
                bg[j] = *(const bf16x8*)&gsb[lo];
                bu[j] = *(const bf16x8*)&usb[lo];
            }
#pragma unroll
            for (int i = 0; i < 4; i++)
#pragma unroll
                for (int j = 0; j < 2; j++) {
                    accg[i][j] = MFMA_BF16(af[i], bg[j], accg[i][j], 0, 0, 0);
                    accu[i][j] = MFMA_BF16(af[i], bu[j], accu[i][j], 0, 0, 0);
                }
        }
    }

    // epilogue: silu(g)*u -> bf16 act rows
#pragma unroll
    for (int i = 0; i < 4; i++)
#pragma unroll
        for (int j = 0; j < 2; j++)
#pragma unroll
            for (int r = 0; r < 4; r++) {
                int m = wm + i * 16 + qd * 4 + r;
                if (base + m < cnt) {
                    float g = accg[i][j][r], u = accu[i][j][r];
                    float a = g / (1.f + __expf(-g)) * u;
                    act[(size_t)(arow0 + m) * ID + nb0 + wn + j * 16 + l16] = f2bf(a);
                }
            }
}

// ---------------- kernel 4: GEMM2 (act @ down^T -> yexp bf16) -------------
// grid (h_slices=8, m_tiles=16, experts=16). block tile M=128 x N=128,
// BK=64, wave 64x64. Double-buffered global_load_lds. Atomic-free epilogue.
__global__ __launch_bounds__(256) void gemm2_k(
        const short* __restrict__ act,
        const short* __restrict__ dpb,
        const int* __restrict__ counts,
        const int* __restrict__ offs,
        short* __restrict__ yexp) {
    __shared__ short as_[2 * 128 * BK];
    __shared__ short ds_[2 * 128 * BK];

    int e = blockIdx.z;
    int cnt = counts[e];
    int base = blockIdx.y * 128;
    if (base >= cnt) return;
    int arow0 = offs[e] + base;

    int tid = threadIdx.x;
    int wv = tid >> 6, lane = tid & 63;
    int qd = lane >> 4, l16 = lane & 15;
    int wm = (wv >> 1) * 64, wn = (wv & 1) * 64;
    int hb0 = blockIdx.x * 128;
    const short* dp = dpb + (size_t)e * HD * ID + (size_t)hb0 * ID;

    const short* asg[4]; const short* dsg[4]; short* ald[4]; short* dld[4];
#pragma unroll
    for (int i = 0; i < 4; i++) {
        int idx = i * 256 + tid, r = idx >> 3, c = idx & 7;
        int sw = ((c ^ r) & 7) << 3;
        asg[i] = act + (size_t)(arow0 + r) * ID + sw;
        dsg[i] = dp + (size_t)r * ID + sw;
        ald[i] = &as_[(i * 256 + wv * 64) * 8];
        dld[i] = &ds_[(i * 256 + wv * 64) * 8];
    }

    f32x4 acc[4][4] = {};

    // pre-issue panel 0 into buffer 0
#pragma unroll
    for (int i = 0; i < 4; i++) {
        load_lds16(asg[i], ald[i]);
        load_lds16(dsg[i], dld[i]);
    }

    for (int kpi = 0; kpi < ID / BK; kpi++) {
        __syncthreads();
        if (kpi + 1 < ID / BK) {
            int kn = (kpi + 1) * BK;
            int o = ((kpi + 1) & 1) * 128 * BK;
#pragma unroll
            for (int i = 0; i < 4; i++) {
                load_lds16(asg[i] + kn, ald[i] + o);
                load_lds16(dsg[i] + kn, dld[i] + o);
            }
        }
        const short* asb = &as_[(kpi & 1) * 128 * BK];
        const short* dsb = &ds_[(kpi & 1) * 128 * BK];
#pragma unroll
        for (int ks = 0; ks < 2; ks++) {
            int cb = ks * 4 + qd;
            bf16x8 af[4], bd[4];
#pragma unroll
            for (int i = 0; i < 4; i++) {
                int r = wm + i * 16 + l16;
                af[i] = *(const bf16x8*)&asb[(r << 6) + (((cb ^ r) & 7) << 3)];
                int r2 = wn + i * 16 + l16;
                bd[i] = *(const bf16x8*)&dsb[(r2 << 6) + (((cb ^ r2) & 7) << 3)];
            }
#pragma unroll
            for (int i = 0; i < 4; i++)
#pragma unroll
                for (int j = 0; j < 4; j++)
                    acc[i][j] = MFMA_BF16(af[i], bd[j], acc[i][j], 0, 0, 0);
        }
    }

#pragma unroll
    for (int i = 0; i < 4; i++)
#pragma unroll
        for (int j = 0; j < 4; j++)
#pragma unroll
            for (int r = 0; r < 4; r++) {
                int m = wm + i * 16 + qd * 4 + r;
                if (base + m < cnt)
                    yexp[(size_t)(arow0 + m) * HD + hb0 + wn + j * 16 + l16] =
                        f2bf(acc[i][j][r]);
            }
}

// ---------------- kernel 5: weighted combine (atomic-free) ----------------
// 2 tokens per block; thread covers 8 cols. Fully overwrites out.
__global__ __launch_bounds__(256) void combine_k(
        const short* __restrict__ yexp,
        const int* __restrict__ offs,
        const int* __restrict__ tk_idx, const float* __restrict__ tk_w,
        const int* __restrict__ pair_slot,
        float* __restrict__ out) {
    int t = blockIdx.x * 2 + (threadIdx.x >> 7);
    int i = threadIdx.x & 127;          // col group of 8
    float acc[8] = {};
#pragma unroll
    for (int k = 0; k < TOPK; k++) {
        int p = t * TOPK + k;
        int e = tk_idx[p];
        int row = offs[e] + pair_slot[p];
        float w = tk_w[p];
        bf16x8 v = *(const bf16x8*)(yexp + (size_t)row * HD + i * 8);
#pragma unroll
        for (int j = 0; j < 8; j++) acc[j] += w * bf2f(v[j]);
    }
    float4 o0 = {acc[0], acc[1], acc[2], acc[3]};
    float4 o1 = {acc[4], acc[5], acc[6], acc[7]};
    float* d = out + (size_t)t * HD + i * 8;
    *(float4*)d = o0;
    *(float4*)(d + 4) = o1;
}

// ---------------- launch ----------------
extern "C" void kernel_launch(void* const* d_in, const int* in_sizes, int n_in,
                              void* d_out, int out_size, void* d_ws, size_t ws_size,
                              hipStream_t stream) {
    const float* x  = (const float*)d_in[0];   // hidden_states [T,H]
    const float* gw = (const float*)d_in[1];   // gate_weight  [E,H]
    const float* eb = (const float*)d_in[2];   // e_bias       [E]
    const float* gp = (const float*)d_in[3];   // gate_proj [E,I,H]
    const float* up = (const float*)d_in[4];   // up_proj   [E,I,H]
    const float* dp = (const float*)d_in[5];   // down_proj [E,H,I]

    short* gpb = (short*)d_ws;                  // bf16 weights: 3 x 16.8 MB
    short* upb = gpb + WELEM;
    short* dpb = upb + WELEM;
    short* xb  = dpb + WELEM;                   // x bf16: 2048x1024
    short* act = xb + (size_t)T_TOK * HD;       // (8192+128) x 512 bf16
    int* counts    = (int*)(act + (size_t)(T_TOK * TOPK + 128) * ID);
    int* offs      = counts + NE;
    int* tok_list  = offs + NE;                       // E*T
    int* pair_slot = tok_list + NE * T_TOK;           // T*4
    int* tk_idx    = pair_slot + T_TOK * TOPK;        // T*4
    float* tk_w    = (float*)(tk_idx + T_TOK * TOPK); // T*4
    // yexp bf16 (8192 x 1024 = 16.8 MB) aliases gpb (dead after gemm1;
    // exact size match). Same-stream ordering makes this safe.
    short* yexp = gpb;

    hipMemsetAsync(counts, 0, NE * sizeof(int), stream);

    conv_k<<<dim3(WELEM / 8 / 256, 3), 256, 0, stream>>>(gp, gpb, up, upb,
                                                         dp, dpb);
    router_k<<<T_TOK / 4, 256, 0, stream>>>(x, gw, eb, tk_idx, tk_w, xb);
    assign_k<<<T_TOK * TOPK / 256, 256, 0, stream>>>(tk_idx, counts,
                                                     tok_list, pair_slot);
    offs_k<<<1, 64, 0, stream>>>(counts, offs);
    gemm1_k<<<dim3(ID / 64, T_TOK / 128, NE), 256, 0, stream>>>(
        xb, gpb, upb, counts, offs, tok_list, act);
    gemm2_k<<<dim3(HD / 128, T_TOK / 128, NE), 256, 0, stream>>>(
        act, dpb, counts, offs, yexp);
    combine_k<<<T_TOK / 2, 256, 0, stream>>>(yexp, offs, tk_idx, tk_w,
                                             pair_slot, (float*)d_out);
}